// Round 23
// baseline (107.561 us; speedup 1.0000x reference)
//
#include <hip/hip_runtime.h>

#define CDIM 64
#define KCODES 1024
#define ZQ_ELEMS (32 * 64 * 64 * 64)  // 8388608
#define NROWS 131072
#define FLT_BIG 3.402823466e38f
#define RPB 128                       // rows per block (screen)
#define NBLK (NROWS / RPB)            // 1024
#define DELTA 5e-4f                   // screen slack; err bound ~2e-4 (z_lo+e_lo dropped)

// ws layout: [0,8KB) part(512 dbl) | [16KB,20KB) Bsq | [32KB,+128KB) e1 | +8KB pad
//            [256KB, +25.2MB) keys[NROWS][48]
#define WS_BSQ_OFF 16384
#define WS_E1_OFF  32768
#define WS_KEY_OFF 262144

// screen LDS (bytes): frags 16*65*16=16640 @0 | e-dbuf 2x4096 @16640 | sB @24832
#define E_OFF     16640
#define B_OFF     24832
#define SU_BYTES  28928

typedef __bf16 bf16x8 __attribute__((ext_vector_type(8)));
typedef float  f32x4  __attribute__((ext_vector_type(4)));

// numpy-exact pairwise sum of squares (8 accumulators, numpy pairwise order)
__device__ __forceinline__ float pairwise_sq64(const float* v) {
    float r[8];
    #pragma unroll
    for (int j = 0; j < 8; ++j) r[j] = __fmul_rn(v[j], v[j]);
    #pragma unroll
    for (int m = 1; m < 8; ++m) {
        #pragma unroll
        for (int j = 0; j < 8; ++j)
            r[j] = __fadd_rn(r[j], __fmul_rn(v[8 * m + j], v[8 * m + j]));
    }
    return __fadd_rn(__fadd_rn(__fadd_rn(r[0], r[1]), __fadd_rn(r[2], r[3])),
                     __fadd_rn(__fadd_rn(r[4], r[5]), __fadd_rn(r[6], r[7])));
}

// ---------------- prep: exact code norms + bf16 codebook, B-fragment layout ----
__global__ __launch_bounds__(256) void vq_prep(const float* __restrict__ cb,
                                               float* __restrict__ Bsq,
                                               __bf16* __restrict__ e1) {
    const int k = blockIdx.x * 256 + threadIdx.x;   // 4 blocks -> 1024 codes
    const float* __restrict__ ck = cb + k * CDIM;
    float v[CDIM];
    #pragma unroll
    for (int q = 0; q < 16; ++q) {
        float4 t = ((const float4*)ck)[q];
        v[4 * q + 0] = t.x; v[4 * q + 1] = t.y; v[4 * q + 2] = t.z; v[4 * q + 3] = t.w;
    }
    Bsq[k] = pairwise_sq64(v);

    const int t = k >> 4, kin = k & 15;
    bf16x8* F1 = (bf16x8*)e1;
    #pragma unroll
    for (int ks = 0; ks < 2; ++ks) {
        #pragma unroll
        for (int g = 0; g < 4; ++g) {
            bf16x8 a;
            #pragma unroll
            for (int i = 0; i < 8; ++i) a[i] = (__bf16)v[ks * 32 + 8 * g + i];
            F1[(t * 2 + ks) * 64 + ((g << 4) | kin)] = a;
        }
    }
}

// branchless sorted-3 insert: fmaf + pack + min + 2*med3
#define INS(s, j, accv, Bv, code0) \
    { \
        const float vv = __fmaf_rn(-2.f, (accv), (Bv)); \
        const float kk = __int_as_float((__float_as_int(vv) & 0xFFFFFC00) | (code0)); \
        const float o0 = K0[s][j], o1 = K1[s][j], o2 = K2[s][j]; \
        K0[s][j] = fminf(o0, kk); \
        K1[s][j] = __builtin_amdgcn_fmed3f(o0, o1, kk); \
        K2[s][j] = __builtin_amdgcn_fmed3f(o1, o2, kk); \
    }

// one 16-code tile: 4 MFMA (2 row-sets, chained over K) + 8 inserts; e from LDS
#define TILE_COMPUTE(Ea, Eb, code0) \
    { \
        const float Bv = sB[code0]; \
        f32x4 a0 = __builtin_amdgcn_mfma_f32_16x16x32_bf16(zh00, Ea, zero, 0, 0, 0); \
        a0       = __builtin_amdgcn_mfma_f32_16x16x32_bf16(zh01, Eb, a0, 0, 0, 0); \
        f32x4 a1 = __builtin_amdgcn_mfma_f32_16x16x32_bf16(zh10, Ea, zero, 0, 0, 0); \
        a1       = __builtin_amdgcn_mfma_f32_16x16x32_bf16(zh11, Eb, a1, 0, 0, 0); \
        INS(0, 0, a0[0], Bv, code0) INS(0, 1, a0[1], Bv, code0) \
        INS(0, 2, a0[2], Bv, code0) INS(0, 3, a0[3], Bv, code0) \
        INS(1, 0, a1[0], Bv, code0) INS(1, 1, a1[1], Bv, code0) \
        INS(1, 2, a1[2], Bv, code0) INS(1, 3, a1[3], Bv, code0) \
    }

// ---------------- screen kernel: MFMA screen only; keys -> global ----------------
__global__ __launch_bounds__(256, 4) void vq_screen(const float* __restrict__ z,
                                                    const float* __restrict__ Bsq,
                                                    const __bf16* __restrict__ e1,
                                                    float* __restrict__ keys) {
    __shared__ __align__(16) unsigned char sU[SU_BYTES];
    float* __restrict__ sB = (float*)(sU + B_OFF);

    const int tid = threadIdx.x;
    const int n0 = blockIdx.x * RPB;
    const int b = n0 >> 12;
    const int hw0 = n0 & 4095;
    const float* __restrict__ zb = z + ((size_t)b << 18) + hw0;

    for (int k = tid; k < KCODES; k += 256) sB[k] = Bsq[k];

    // phase 0: z staging into bf16-hi fragment planes + e-chunk 0
    {
        bf16x8* __restrict__ zfw = (bf16x8*)sU;
        const int r = tid & 127;
        const int h = tid >> 7;
        const int w = r >> 5, s = (r >> 4) & 1, li = r & 15;
        #pragma unroll
        for (int g = 0; g < 4; ++g) {
            bf16x8 hi;
            #pragma unroll
            for (int i = 0; i < 8; ++i) {
                const float fv = zb[((size_t)(32 * h + 8 * g + i) << 12) + r];
                hi[i] = (__bf16)fv;
            }
            zfw[(w * 4 + s * 2 + h) * 65 + ((g << 4) | li)] = hi;
        }
        *(float4*)(sU + E_OFF + tid * 16) =
            *(const float4*)((const unsigned char*)e1 + tid * 16);
    }
    __syncthreads();

    const int lane = tid & 63, w = tid >> 6;
    const int g = lane >> 4, li = lane & 15;

    const bf16x8* __restrict__ zf = (const bf16x8*)sU;
    const bf16x8 zh00 = zf[(w * 4 + 0) * 65 + lane];
    const bf16x8 zh01 = zf[(w * 4 + 1) * 65 + lane];
    const bf16x8 zh10 = zf[(w * 4 + 2) * 65 + lane];
    const bf16x8 zh11 = zf[(w * 4 + 3) * 65 + lane];

    float K0[2][4], K1[2][4], K2[2][4];
    #pragma unroll
    for (int s = 0; s < 2; ++s)
        #pragma unroll
        for (int j = 0; j < 4; ++j) { K0[s][j] = FLT_BIG; K1[s][j] = FLT_BIG; K2[s][j] = FLT_BIG; }

    const f32x4 zero = {0.f, 0.f, 0.f, 0.f};

    // depth-2 staged, counted-wait-barrier e-stream (round-22 structure)
    float4 vP = *(const float4*)((const unsigned char*)e1 + 4096 + tid * 16);

    for (int c = 0; c < 32; ++c) {
        const float4 vN =
            *(const float4*)((const unsigned char*)e1 + (c + 2) * 4096 + tid * 16);
        *(float4*)(sU + E_OFF + ((c + 1) & 1) * 4096 + tid * 16) = vP;

        const bf16x8* __restrict__ buf = (const bf16x8*)(sU + E_OFF + (c & 1) * 4096);
        const int cb0 = c * 32 + li;
        TILE_COMPUTE(buf[lane],       buf[64 + lane],  cb0)
        TILE_COMPUTE(buf[128 + lane], buf[192 + lane], cb0 + 16)

        vP = vN;
        asm volatile("s_waitcnt lgkmcnt(0)" ::: "memory");
        __builtin_amdgcn_s_barrier();
        __builtin_amdgcn_sched_barrier(0);
    }

    // key write-out: row-major keys[row][48]; 16-lane group writes one row's 192B
    #pragma unroll
    for (int s = 0; s < 2; ++s) {
        #pragma unroll
        for (int j = 0; j < 4; ++j) {
            const int row = 32 * w + 16 * s + 4 * g + j;
            float* __restrict__ gk = keys + (size_t)(n0 + row) * 48 + li * 3;
            gk[0] = K0[s][j];
            gk[1] = K1[s][j];
            gk[2] = K2[s][j];
        }
    }
}

// ---------------- rescue kernel: exact numpy-semantics argmin, 1 thread/row ----
__global__ __launch_bounds__(256) void vq_rescue(const float* __restrict__ z,
                                                 const float* __restrict__ cb,
                                                 const float* __restrict__ Bsq,
                                                 const float* __restrict__ keys,
                                                 float* __restrict__ zq_out,
                                                 float* __restrict__ idx_out,
                                                 double* __restrict__ part) {
    __shared__ double sW[4];
    const int tid = threadIdx.x;
    const int n = blockIdx.x * 256 + tid;       // 512 blocks x 256 = 131072 rows
    const int b = n >> 12;
    const int hw = n & 4095;

    const float* __restrict__ krow = keys + (size_t)n * 48;

    // pass 1: gmin (float4 reads, keys stay out of long-lived registers)
    float gmin = FLT_BIG;
    #pragma unroll
    for (int q = 0; q < 12; ++q) {
        float4 kv4 = ((const float4*)krow)[q];
        gmin = fminf(gmin, fminf(fminf(kv4.x, kv4.y), fminf(kv4.z, kv4.w)));
    }
    const float thr = gmin + DELTA;

    float zrow[CDIM];
    const float* __restrict__ zp = z + ((size_t)b << 18) + hw;
    #pragma unroll
    for (int c = 0; c < CDIM; ++c) zrow[c] = zp[(size_t)c << 12];  // coalesced
    const float A = pairwise_sq64(zrow);

    // pass 2: exact eval of candidates (L2-hot key re-read)
    float bd = FLT_BIG;
    int bk = 1 << 30;
    for (int s2 = 0; s2 < 48; ++s2) {
        const float kv = krow[s2];
        if (kv <= thr) {
            const int k = __float_as_int(kv) & 0x3FF;
            const float4* __restrict__ ek = (const float4*)(cb + (size_t)k * CDIM);
            float m = 0.f;
            #pragma unroll
            for (int q = 0; q < 16; ++q) {      // BLAS order: sequential in c
                float4 e = ek[q];
                m = __fmaf_rn(zrow[4 * q + 0], e.x, m);
                m = __fmaf_rn(zrow[4 * q + 1], e.y, m);
                m = __fmaf_rn(zrow[4 * q + 2], e.z, m);
                m = __fmaf_rn(zrow[4 * q + 3], e.w, m);
            }
            const float d = __fsub_rn(__fadd_rn(A, Bsq[k]), __fadd_rn(m, m));
            if (d < bd || (d == bd && k < bk)) { bd = d; bk = k; }
        }
    }

    idx_out[n] = (float)bk;

    const float4* __restrict__ cq = (const float4*)(cb + (size_t)bk * CDIM);
    float* __restrict__ zo = zq_out + ((size_t)b << 18) + hw;
    float lsum = 0.f;
    #pragma unroll
    for (int q = 0; q < 16; ++q) {
        float4 qv = cq[q];
        zo[(size_t)(4 * q + 0) << 12] = qv.x;
        zo[(size_t)(4 * q + 1) << 12] = qv.y;
        zo[(size_t)(4 * q + 2) << 12] = qv.z;
        zo[(size_t)(4 * q + 3) << 12] = qv.w;
        lsum = fmaf(qv.x - zrow[4 * q + 0], qv.x - zrow[4 * q + 0], lsum);
        lsum = fmaf(qv.y - zrow[4 * q + 1], qv.y - zrow[4 * q + 1], lsum);
        lsum = fmaf(qv.z - zrow[4 * q + 2], qv.z - zrow[4 * q + 2], lsum);
        lsum = fmaf(qv.w - zrow[4 * q + 3], qv.w - zrow[4 * q + 3], lsum);
    }

    double ls = (double)lsum;
    for (int off = 32; off > 0; off >>= 1) ls += __shfl_down(ls, off, 64);
    if ((tid & 63) == 0) sW[tid >> 6] = ls;
    __syncthreads();
    if (tid == 0) part[blockIdx.x] = sW[0] + sW[1] + sW[2] + sW[3];
}

__global__ void vq_finalize(const double* __restrict__ part, float* __restrict__ loss_out) {
    __shared__ double s[8];
    const int tid = threadIdx.x;       // 512 threads, one block
    double v = part[tid];
    for (int off = 32; off > 0; off >>= 1) v += __shfl_down(v, off, 64);
    if ((tid & 63) == 0) s[tid >> 6] = v;
    __syncthreads();
    if (tid == 0) {
        double t = 0.0;
        #pragma unroll
        for (int i = 0; i < 8; ++i) t += s[i];
        // loss = codebook_loss + 0.25*commitment = 1.25 * mean((z_q - z)^2)
        *loss_out = (float)(1.25 * t / (double)ZQ_ELEMS);
    }
}

extern "C" void kernel_launch(void* const* d_in, const int* in_sizes, int n_in,
                              void* d_out, int out_size, void* d_ws, size_t ws_size,
                              hipStream_t stream) {
    const float* z  = (const float*)d_in[0];
    const float* cb = (const float*)d_in[1];
    float* out  = (float*)d_out;
    float* zq   = out;                       // 8388608
    float* loss = out + ZQ_ELEMS;            // 1
    float* idx  = out + ZQ_ELEMS + 1;        // 131072
    char* ws = (char*)d_ws;
    double* part = (double*)ws;              // 512 doubles
    float* Bsq   = (float*)(ws + WS_BSQ_OFF);
    __bf16* e1   = (__bf16*)(ws + WS_E1_OFF);
    float* keys  = (float*)(ws + WS_KEY_OFF);   // 131072 x 48 f32 = 25.2 MB

    vq_prep<<<4, 256, 0, stream>>>(cb, Bsq, e1);
    vq_screen<<<NBLK, 256, 0, stream>>>(z, Bsq, e1, keys);
    vq_rescue<<<512, 256, 0, stream>>>(z, cb, Bsq, keys, zq, idx, part);
    vq_finalize<<<1, 512, 0, stream>>>(part, loss);
}

// Round 24
// 67.471 us; speedup vs baseline: 1.5942x; 1.5942x over previous
//
#include <hip/hip_runtime.h>

#define CDIM 64
#define KCODES 1024
#define ZQ_ELEMS (32 * 64 * 64 * 64)  // 8388608
#define NROWS 131072
#define FLT_BIG 3.402823466e38f
#define RPB 128                       // rows per block
#define NBLK (NROWS / RPB)            // 1024
#define CSTRIDE 49                    // sKey row stride (floats); 48 slots used
#define DELTA 5e-4f                   // screen slack; err bound ~2e-4 (z_lo+e_lo dropped)

// ws layout: [0,8KB) part | [16KB,20KB) Bsq | [32KB,+128KB) e1 | +16KB pad (overread)
#define WS_BSQ_OFF 16384
#define WS_E1_OFF  32768

// LDS (bytes): sB @0 (4096) | region @4096:
//   phase0/1: frags 16*65*16=16640 @4096 (end 20736) | e-quad 4x4096 @20736 (end 37120)
//   phase2:   sKey 128*49*4=25088 @4096 (end 29184) | sRd 512 @29184 | sRk 512 @29696
#define B_OFF     0
#define FRAG_OFF  4096
#define E_OFF     20736
#define SKEY_OFF  4096
#define SK_RD_OFF 29184
#define SK_RK_OFF 29696
#define SU_BYTES  37120

typedef __bf16 bf16x8 __attribute__((ext_vector_type(8)));
typedef float  f32x4  __attribute__((ext_vector_type(4)));

// numpy-exact pairwise sum of squares (8 accumulators, numpy pairwise order)
__device__ __forceinline__ float pairwise_sq64(const float* v) {
    float r[8];
    #pragma unroll
    for (int j = 0; j < 8; ++j) r[j] = __fmul_rn(v[j], v[j]);
    #pragma unroll
    for (int m = 1; m < 8; ++m) {
        #pragma unroll
        for (int j = 0; j < 8; ++j)
            r[j] = __fadd_rn(r[j], __fmul_rn(v[8 * m + j], v[8 * m + j]));
    }
    return __fadd_rn(__fadd_rn(__fadd_rn(r[0], r[1]), __fadd_rn(r[2], r[3])),
                     __fadd_rn(__fadd_rn(r[4], r[5]), __fadd_rn(r[6], r[7])));
}

// ---------------- prep: exact code norms + bf16 codebook, B-fragment layout ----
__global__ __launch_bounds__(256) void vq_prep(const float* __restrict__ cb,
                                               float* __restrict__ Bsq,
                                               __bf16* __restrict__ e1) {
    const int k = blockIdx.x * 256 + threadIdx.x;   // 4 blocks -> 1024 codes
    const float* __restrict__ ck = cb + k * CDIM;
    float v[CDIM];
    #pragma unroll
    for (int q = 0; q < 16; ++q) {
        float4 t = ((const float4*)ck)[q];
        v[4 * q + 0] = t.x; v[4 * q + 1] = t.y; v[4 * q + 2] = t.z; v[4 * q + 3] = t.w;
    }
    Bsq[k] = pairwise_sq64(v);

    const int t = k >> 4, kin = k & 15;
    bf16x8* F1 = (bf16x8*)e1;
    #pragma unroll
    for (int ks = 0; ks < 2; ++ks) {
        #pragma unroll
        for (int g = 0; g < 4; ++g) {
            bf16x8 a;
            #pragma unroll
            for (int i = 0; i < 8; ++i) a[i] = (__bf16)v[ks * 32 + 8 * g + i];
            F1[(t * 2 + ks) * 64 + ((g << 4) | kin)] = a;
        }
    }
}

// branchless sorted-3 insert: fmaf + pack + min + 2*med3
#define INS(s, j, accv, Bv, code0) \
    { \
        const float vv = __fmaf_rn(-2.f, (accv), (Bv)); \
        const float kk = __int_as_float((__float_as_int(vv) & 0xFFFFFC00) | (code0)); \
        const float o0 = K0[s][j], o1 = K1[s][j], o2 = K2[s][j]; \
        K0[s][j] = fminf(o0, kk); \
        K1[s][j] = __builtin_amdgcn_fmed3f(o0, o1, kk); \
        K2[s][j] = __builtin_amdgcn_fmed3f(o1, o2, kk); \
    }

// one 16-code tile: 4 MFMA (2 row-sets, chained over K) + 8 inserts; e from LDS
#define TILE_COMPUTE(Ea, Eb, code0) \
    { \
        const float Bv = sB[code0]; \
        f32x4 a0 = __builtin_amdgcn_mfma_f32_16x16x32_bf16(zh00, Ea, zero, 0, 0, 0); \
        a0       = __builtin_amdgcn_mfma_f32_16x16x32_bf16(zh01, Eb, a0, 0, 0, 0); \
        f32x4 a1 = __builtin_amdgcn_mfma_f32_16x16x32_bf16(zh10, Ea, zero, 0, 0, 0); \
        a1       = __builtin_amdgcn_mfma_f32_16x16x32_bf16(zh11, Eb, a1, 0, 0, 0); \
        INS(0, 0, a0[0], Bv, code0) INS(0, 1, a0[1], Bv, code0) \
        INS(0, 2, a0[2], Bv, code0) INS(0, 3, a0[3], Bv, code0) \
        INS(1, 0, a1[0], Bv, code0) INS(1, 1, a1[1], Bv, code0) \
        INS(1, 2, a1[2], Bv, code0) INS(1, 3, a1[3], Bv, code0) \
    }

// ---------------- main: MFMA screen, 2-chunks-per-barrier e-stream + exact rescue ----
// Block = 128 rows (4 waves x 32 rows). e streamed in 32-code chunks through a
// 4-slot (16 KB) LDS buffer: per iteration stage 2 chunks (depth-2, counted-wait)
// and compute 2 chunks -> 16 barriers total instead of 32.
__global__ __launch_bounds__(256, 4) void vq_main(const float* __restrict__ z,
                                                  const float* __restrict__ cb,
                                                  const float* __restrict__ Bsq,
                                                  const __bf16* __restrict__ e1,
                                                  float* __restrict__ zq_out,
                                                  float* __restrict__ idx_out,
                                                  double* __restrict__ part) {
    __shared__ __align__(16) unsigned char sU[SU_BYTES];
    __shared__ double sP2[2];
    float* __restrict__ sB = (float*)(sU + B_OFF);

    const int tid = threadIdx.x;
    const int n0 = blockIdx.x * RPB;
    const int b = n0 >> 12;
    const int hw0 = n0 & 4095;
    const float* __restrict__ zb = z + ((size_t)b << 18) + hw0;

    for (int k = tid; k < KCODES; k += 256) sB[k] = Bsq[k];

    // ---- phase 0: z staging into bf16-hi fragment planes + e-chunks 0,1 ----
    // plane(w,s,H) = w*4+s*2+H ; slot = g*16+li ; row=32w+16s+li ; K=32H+8g+i
    {
        bf16x8* __restrict__ zfw = (bf16x8*)(sU + FRAG_OFF);
        const int r = tid & 127;             // row
        const int h = tid >> 7;              // K half
        const int w = r >> 5, s = (r >> 4) & 1, li = r & 15;
        #pragma unroll
        for (int g = 0; g < 4; ++g) {
            bf16x8 hi;
            #pragma unroll
            for (int i = 0; i < 8; ++i) {
                const float fv = zb[((size_t)(32 * h + 8 * g + i) << 12) + r];
                hi[i] = (__bf16)fv;
            }
            zfw[(w * 4 + s * 2 + h) * 65 + ((g << 4) | li)] = hi;
        }
        // stage e chunks 0,1 (8 KB, coalesced)
        *(float4*)(sU + E_OFF + tid * 16) =
            *(const float4*)((const unsigned char*)e1 + tid * 16);
        *(float4*)(sU + E_OFF + 4096 + tid * 16) =
            *(const float4*)((const unsigned char*)e1 + 4096 + tid * 16);
    }

    // preload chunks 2,3 into registers (issue before the barrier for latency headroom)
    float4 vP0 = *(const float4*)((const unsigned char*)e1 + 2 * 4096 + tid * 16);
    float4 vP1 = *(const float4*)((const unsigned char*)e1 + 3 * 4096 + tid * 16);
    __syncthreads();

    // ---- phase 1: MFMA screen; wave w owns rows [32w,32w+32) x all 1024 codes ----
    const int lane = tid & 63, w = tid >> 6;
    const int g = lane >> 4, li = lane & 15;

    const bf16x8* __restrict__ zf = (const bf16x8*)(sU + FRAG_OFF);
    const bf16x8 zh00 = zf[(w * 4 + 0) * 65 + lane];
    const bf16x8 zh01 = zf[(w * 4 + 1) * 65 + lane];
    const bf16x8 zh10 = zf[(w * 4 + 2) * 65 + lane];
    const bf16x8 zh11 = zf[(w * 4 + 3) * 65 + lane];

    float K0[2][4], K1[2][4], K2[2][4];
    #pragma unroll
    for (int s = 0; s < 2; ++s)
        #pragma unroll
        for (int j = 0; j < 4; ++j) { K0[s][j] = FLT_BIG; K1[s][j] = FLT_BIG; K2[s][j] = FLT_BIG; }

    const f32x4 zero = {0.f, 0.f, 0.f, 0.f};

    for (int i = 0; i < 16; ++i) {
        const int c0 = 2 * i;
        // issue loads for chunks c0+4, c0+5 (i=14,15 overread into ws pad — harmless);
        // these stay in flight across this iteration's barrier (counted wait).
        const float4 vN0 =
            *(const float4*)((const unsigned char*)e1 + (c0 + 4) * 4096 + tid * 16);
        const float4 vN1 =
            *(const float4*)((const unsigned char*)e1 + (c0 + 5) * 4096 + tid * 16);
        // write chunks c0+2, c0+3 (loaded a full iteration ago)
        *(float4*)(sU + E_OFF + ((c0 + 2) & 3) * 4096 + tid * 16) = vP0;
        *(float4*)(sU + E_OFF + ((c0 + 3) & 3) * 4096 + tid * 16) = vP1;

        const bf16x8* __restrict__ bufA = (const bf16x8*)(sU + E_OFF + (c0 & 3) * 4096);
        const bf16x8* __restrict__ bufB = (const bf16x8*)(sU + E_OFF + ((c0 + 1) & 3) * 4096);
        const int cbA = c0 * 32 + li;
        const int cbB = (c0 + 1) * 32 + li;
        TILE_COMPUTE(bufA[lane],       bufA[64 + lane],  cbA)
        TILE_COMPUTE(bufA[128 + lane], bufA[192 + lane], cbA + 16)
        TILE_COMPUTE(bufB[lane],       bufB[64 + lane],  cbB)
        TILE_COMPUTE(bufB[128 + lane], bufB[192 + lane], cbB + 16)

        vP0 = vN0;
        vP1 = vN1;
        // counted-wait barrier: drain LDS ops only; vN loads survive.
        asm volatile("s_waitcnt lgkmcnt(0)" ::: "memory");
        __builtin_amdgcn_s_barrier();
        __builtin_amdgcn_sched_barrier(0);
    }

    __syncthreads();   // full drain once; frag planes + e-buf dead -> reuse region

    float* __restrict__ sKey = (float*)(sU + SKEY_OFF);
    float* __restrict__ sRd = (float*)(sU + SK_RD_OFF);
    int*   __restrict__ sRk = (int*)(sU + SK_RK_OFF);
    #pragma unroll
    for (int s = 0; s < 2; ++s) {
        #pragma unroll
        for (int j = 0; j < 4; ++j) {
            const int row = 32 * w + 16 * s + 4 * g + j;   // local row 0..127
            const int base = row * CSTRIDE + li * 3;
            sKey[base + 0] = K0[s][j];
            sKey[base + 1] = K1[s][j];
            sKey[base + 2] = K2[s][j];
        }
    }
    __syncthreads();

    // ---- phase 2: exact numpy-semantics rescue; 2 threads per row ----
    {
        const int r = tid & 127;
        const int half = tid >> 7;
        const int n = n0 + r;

        float gmin = FLT_BIG;
        #pragma unroll
        for (int s2 = 0; s2 < 48; ++s2) gmin = fminf(gmin, sKey[r * CSTRIDE + s2]);
        const float thr = gmin + DELTA;

        float zrow[CDIM];
        const float* __restrict__ zp = zb + r;
        #pragma unroll
        for (int c = 0; c < CDIM; ++c) zrow[c] = zp[(size_t)c << 12];  // coalesced, L2-hot
        const float A = pairwise_sq64(zrow);

        float bd = FLT_BIG;
        int bk = 1 << 30;
        const int sbeg = half * 24;
        for (int s2 = sbeg; s2 < sbeg + 24; ++s2) {
            const float kv = sKey[r * CSTRIDE + s2];
            if (kv <= thr) {
                const int k = __float_as_int(kv) & 0x3FF;
                const float4* __restrict__ ek = (const float4*)(cb + (size_t)k * CDIM);
                float m = 0.f;
                #pragma unroll
                for (int q = 0; q < 16; ++q) {      // BLAS order: sequential in c
                    float4 e = ek[q];
                    m = __fmaf_rn(zrow[4 * q + 0], e.x, m);
                    m = __fmaf_rn(zrow[4 * q + 1], e.y, m);
                    m = __fmaf_rn(zrow[4 * q + 2], e.z, m);
                    m = __fmaf_rn(zrow[4 * q + 3], e.w, m);
                }
                const float d = __fsub_rn(__fadd_rn(A, sB[k]), __fadd_rn(m, m));
                if (d < bd || (d == bd && k < bk)) { bd = d; bk = k; }
            }
        }

        if (half == 1) { sRd[r] = bd; sRk[r] = bk; }
        __syncthreads();

        if (tid < RPB) {
            const float d1 = sRd[r];
            const int   k1 = sRk[r];
            if (d1 < bd || (d1 == bd && k1 < bk)) { bd = d1; bk = k1; }  // lex-min combine

            idx_out[n] = (float)bk;

            const float4* __restrict__ cq = (const float4*)(cb + (size_t)bk * CDIM);
            float* __restrict__ zo = zq_out + ((size_t)b << 18) + hw0 + r;
            float lsum = 0.f;
            #pragma unroll
            for (int q = 0; q < 16; ++q) {
                float4 qv = cq[q];
                zo[(size_t)(4 * q + 0) << 12] = qv.x;
                zo[(size_t)(4 * q + 1) << 12] = qv.y;
                zo[(size_t)(4 * q + 2) << 12] = qv.z;
                zo[(size_t)(4 * q + 3) << 12] = qv.w;
                lsum = fmaf(qv.x - zrow[4 * q + 0], qv.x - zrow[4 * q + 0], lsum);
                lsum = fmaf(qv.y - zrow[4 * q + 1], qv.y - zrow[4 * q + 1], lsum);
                lsum = fmaf(qv.z - zrow[4 * q + 2], qv.z - zrow[4 * q + 2], lsum);
                lsum = fmaf(qv.w - zrow[4 * q + 3], qv.w - zrow[4 * q + 3], lsum);
            }

            double ls = (double)lsum;
            for (int off = 32; off > 0; off >>= 1) ls += __shfl_down(ls, off, 64);
            if ((tid & 63) == 0) sP2[tid >> 6] = ls;
        }
    }
    __syncthreads();
    if (tid == 0) part[blockIdx.x] = sP2[0] + sP2[1];
}

__global__ void vq_finalize(const double* __restrict__ part, float* __restrict__ loss_out) {
    __shared__ double s[16];
    const int tid = threadIdx.x;       // 1024 threads, one block
    double v = part[tid];
    for (int off = 32; off > 0; off >>= 1) v += __shfl_down(v, off, 64);
    if ((tid & 63) == 0) s[tid >> 6] = v;
    __syncthreads();
    if (tid == 0) {
        double t = 0.0;
        #pragma unroll
        for (int i = 0; i < 16; ++i) t += s[i];
        // loss = codebook_loss + 0.25*commitment = 1.25 * mean((z_q - z)^2)
        *loss_out = (float)(1.25 * t / (double)ZQ_ELEMS);
    }
}

extern "C" void kernel_launch(void* const* d_in, const int* in_sizes, int n_in,
                              void* d_out, int out_size, void* d_ws, size_t ws_size,
                              hipStream_t stream) {
    const float* z  = (const float*)d_in[0];
    const float* cb = (const float*)d_in[1];
    float* out  = (float*)d_out;
    float* zq   = out;                       // 8388608
    float* loss = out + ZQ_ELEMS;            // 1
    float* idx  = out + ZQ_ELEMS + 1;        // 131072
    char* ws = (char*)d_ws;
    double* part = (double*)ws;              // 1024 doubles
    float* Bsq   = (float*)(ws + WS_BSQ_OFF);
    __bf16* e1   = (__bf16*)(ws + WS_E1_OFF);

    vq_prep<<<4, 256, 0, stream>>>(cb, Bsq, e1);
    vq_main<<<NBLK, 256, 0, stream>>>(z, cb, Bsq, e1, zq, idx, part);
    vq_finalize<<<1, 1024, 0, stream>>>(part, loss);
}